// Round 6
// baseline (394.108 us; speedup 1.0000x reference)
//
#include <hip/hip_runtime.h>
#include <math.h>

#define NB 32
#define NP 24656
#define NO 16
#define NC 81
#define ND 85   // 4 + NC
#define THRESH_F 0.5f
#define NEGPOS_I 3
#define VAR0_F 0.1f
#define VAR1_F 0.2f
#define NEG_HUGE -1e30f

#define BPCNT (NB * NP)
#define MBLK 97          // k_match blocks per batch row = ceil(NP/256)

typedef unsigned long long u64;

// ---------------------------------------------------------------- init
__global__ void k_init(int* __restrict__ npos, float* __restrict__ accB) {
    int t = threadIdx.x;
    if (t < NB) npos[t] = 0;
    if (t < 2 * NB) accB[t] = 0.f;
}

// ---------------------------------------------------------------- match
__global__ __launch_bounds__(256) void k_match(
    const float* __restrict__ tboxes, const float* __restrict__ priors,
    float2* __restrict__ bt2, u64* __restrict__ mcand) {
    const int b = blockIdx.y;
    const int bx = blockIdx.x;
    const int tid = threadIdx.x;
    const int p = bx * 256 + tid;
    const int lane = tid & 63;
    const int wv = tid >> 6;
    __shared__ float tb[NO * 4];
    __shared__ u64 wkey[4][NO];
    if (tid < NO * 4) tb[tid] = tboxes[b * NO * 4 + tid];
    __syncthreads();

    const bool valid = (p < NP);
    float4 pr = make_float4(0.f, 0.f, 1.f, 1.f);
    if (valid) pr = *(const float4*)(priors + (size_t)p * 4);
    const float pl = pr.x - pr.z * 0.5f, pt = pr.y - pr.w * 0.5f;
    const float prr = pr.x + pr.z * 0.5f, pb = pr.y + pr.w * 0.5f;
    const float parea = (prr - pl) * (pb - pt);

    float bestv = -1.f;
    int besti = 0;
    for (int o = 0; o < NO; ++o) {
        const float al = tb[o * 4 + 0], at = tb[o * 4 + 1];
        const float ar = tb[o * 4 + 2], ab = tb[o * 4 + 3];
        float iw = fminf(ar, prr) - fmaxf(al, pl); iw = fmaxf(iw, 0.f);
        float ih = fminf(ab, pb) - fmaxf(at, pt); ih = fmaxf(ih, 0.f);
        const float inter = iw * ih;
        const float aarea = (ar - al) * (ab - at);
        float iou = inter / (aarea + parea - inter);
        if (!valid) iou = -1.f;
        if (iou > bestv) { bestv = iou; besti = o; }

        float m = iou;
        for (int d = 1; d < 64; d <<= 1) m = fmaxf(m, __shfl_xor(m, d, 64));
        u64 key = 0ull;
        if (m >= 0.f) {
            unsigned long long msk = __ballot(iou == m);
            int lam = __ffsll(msk) - 1;
            int pw = bx * 256 + (tid & ~63) + lam;
            key = ((u64)__float_as_uint(m) << 32) |
                  (u64)(0xFFFFFFFFu - (unsigned)pw);
        }
        if (lane == 0) wkey[wv][o] = key;
    }
    if (valid)
        bt2[(size_t)b * NP + p] = make_float2(bestv, __int_as_float(besti));
    __syncthreads();
    if (tid < NO) {
        u64 k0 = wkey[0][tid];
        k0 = (wkey[1][tid] > k0) ? wkey[1][tid] : k0;
        k0 = (wkey[2][tid] > k0) ? wkey[2][tid] : k0;
        k0 = (wkey[3][tid] > k0) ? wkey[3][tid] : k0;
        mcand[((size_t)(b * NO + tid)) * MBLK + bx] = k0;
    }
}

// ---------------------------------------------------------------- scatter
__global__ __launch_bounds__(512) void k_scatter(const u64* __restrict__ mcand,
                                                 float2* __restrict__ bt2) {
    __shared__ int pbest[NB * NO];
    const int t = threadIdx.x;
    const u64* c = mcand + (size_t)t * MBLK;
    u64 best = 0ull;
    for (int i = 0; i < MBLK; ++i) {
        u64 v = c[i];
        best = (v > best) ? v : best;
    }
    pbest[t] = (int)(0xFFFFFFFFu - (unsigned)(best & 0xFFFFFFFFull));
    __syncthreads();
    if (t < NB) {
        for (int o = 0; o < NO; ++o) {
            int p = pbest[t * NO + o];
            bt2[(size_t)t * NP + p] = make_float2(2.0f, __int_as_float(o));
        }
    }
}

// ---------------------------------------------------------------- main fused
// Quad-per-row, straight from global, no LDS, no syncthreads.
// Lane l: row w=l>>2 (64 rows/block), quad-slot q=l&3. Aligned f4 slots
// s=q+4k (A=21r+(r>>2) trick): wave-instr touches 16 rows x 16B contiguous
// per quad => ~16 cache lines/instr (vs 64 for lane-per-row). 6 independent
// loads in flight per lane. Validity: row dword d=4s+t-c0 in [4,84].
__global__ __launch_bounds__(256) void k_main(
    const float* __restrict__ pred, const float* __restrict__ tboxes,
    const int* __restrict__ tlabels, const float* __restrict__ priors,
    const float2* __restrict__ bt2,
    float* __restrict__ lr, int* __restrict__ npos, float* __restrict__ accB) {
    const int b = blockIdx.y;
    const int r0 = blockIdx.x * 64;
    const int tid = threadIdx.x;
    const int w = tid >> 2, q = tid & 3;
    const int nrows = min(64, NP - r0);
    const bool active = (w < nrows);
    const int r = active ? (r0 + w) : (NP - 1);
    const size_t bbase = (size_t)b * NP;
    const float* base = pred + bbase * ND;
    const int A = 21 * r + (r >> 2);
    const int c0 = r & 3;
    const float4* vp = (const float4*)base + A;

    // 6 independent strided loads: slots s = q+4k (clamped to 21)
    float4 v[6];
#pragma unroll
    for (int k = 0; k < 6; ++k) {
        const int s = q + 4 * k;
        v[k] = vp[(s <= 21) ? s : 21];
    }

    // mask + local max/sum. d = 4s + t - c0 is the row dword; class iff 4<=d<=84.
    float vals[24];
#pragma unroll
    for (int k = 0; k < 6; ++k) {
        const int s = q + 4 * k;
        const bool slot_ok = (s <= 21);
        const float xs[4] = {v[k].x, v[k].y, v[k].z, v[k].w};
#pragma unroll
        for (int t = 0; t < 4; ++t) {
            const int d = 4 * s + t - c0;
            vals[4 * k + t] = (slot_ok && d >= 4 && d <= 84) ? xs[t] : NEG_HUGE;
        }
    }
    float mx = vals[0];
#pragma unroll
    for (int j = 1; j < 24; ++j) mx = fmaxf(mx, vals[j]);
    mx = fmaxf(mx, __shfl_xor(mx, 1, 64));
    mx = fmaxf(mx, __shfl_xor(mx, 2, 64));
    float s0 = 0.f, s1 = 0.f;
#pragma unroll
    for (int j = 0; j < 24; j += 2) {
        s0 += __expf(vals[j] - mx);
        s1 += __expf(vals[j + 1] - mx);
    }
    float ssum = s0 + s1;
    ssum += __shfl_xor(ssum, 1, 64);
    ssum += __shfl_xor(ssum, 2, 64);
    const float lse = mx + __logf(ssum);

    // owner lane q==1 holds slot 1: bg = component c0 of its k=0 load
    float my_ll = 0.f, my_ce = 0.f;
    int my_np = 0;
    if (q == 1 && active) {
        const float bg = (c0 == 0) ? v[0].x : (c0 == 1) ? v[0].y
                       : (c0 == 2) ? v[0].z : v[0].w;
        const int p = r0 + w;
        const float2 bt = bt2[bbase + p];
        const bool pos = (bt.x >= THRESH_F);
        const int o = __float_as_int(bt.y);
        lr[bbase + p] = pos ? 0.f : (lse - bg);
        if (pos) {
            my_np = 1;
            const int lbl = tlabels[b * NO + o] + 1;
            my_ce = lse - base[(size_t)r * ND + 4 + lbl];  // cache hit, rare
            const float4 pr = *((const float4*)priors + p);
            const float tx0 = tboxes[(b * NO + o) * 4 + 0];
            const float ty0 = tboxes[(b * NO + o) * 4 + 1];
            const float tx1 = tboxes[(b * NO + o) * 4 + 2];
            const float ty1 = tboxes[(b * NO + o) * 4 + 3];
            const float g0 = ((tx0 + tx1) * 0.5f - pr.x) / (VAR0_F * pr.z);
            const float g1 = ((ty0 + ty1) * 0.5f - pr.y) / (VAR0_F * pr.w);
            const float g2 = __logf((tx1 - tx0) / pr.z) / VAR1_F;
            const float g3 = __logf((ty1 - ty0) / pr.w) / VAR1_F;
            const float l0 = base[(size_t)r * ND + 0];
            const float l1 = base[(size_t)r * ND + 1];
            const float l2 = base[(size_t)r * ND + 2];
            const float l3 = base[(size_t)r * ND + 3];
            float dd, ad;
            dd = l0 - g0; ad = fabsf(dd); my_ll += (ad < 1.f) ? 0.5f * dd * dd : (ad - 0.5f);
            dd = l1 - g1; ad = fabsf(dd); my_ll += (ad < 1.f) ? 0.5f * dd * dd : (ad - 0.5f);
            dd = l2 - g2; ad = fabsf(dd); my_ll += (ad < 1.f) ? 0.5f * dd * dd : (ad - 0.5f);
            dd = l3 - g3; ad = fabsf(dd); my_ll += (ad < 1.f) ? 0.5f * dd * dd : (ad - 0.5f);
        }
    }
    for (int d2 = 1; d2 < 64; d2 <<= 1) {
        my_ll += __shfl_xor(my_ll, d2, 64);
        my_ce += __shfl_xor(my_ce, d2, 64);
        my_np += __shfl_xor(my_np, d2, 64);
    }
    if ((tid & 63) == 0) {
        if (my_ll != 0.f) atomicAdd(&accB[b * 2 + 0], my_ll);
        if (my_ce != 0.f) atomicAdd(&accB[b * 2 + 1], my_ce);
        if (my_np) atomicAdd(&npos[b], my_np);
    }
}

// ---------------------------------------------------------------- select
__global__ __launch_bounds__(1024) void k_select(
    const float* __restrict__ lrk, const int* __restrict__ npos,
    float* __restrict__ accB) {
    const int b = blockIdx.x;
    const float* row = lrk + (size_t)b * NP;
    const int tid = threadIdx.x;
    const int lane = tid & 63;
    const int wid = tid >> 6;

    __shared__ unsigned whist[16][256];
    __shared__ unsigned chist[256];
    __shared__ int sh_bucket, sh_knew;
    __shared__ float wsum[16];
    __shared__ int wcnt[16];

    const int K0 = min(npos[b] * NEGPOS_I, NP);
    int k = K0;
    unsigned prefix = 0;

    for (int shift = 24; shift >= 0; shift -= 8) {
        for (int j = lane; j < 256; j += 64) whist[wid][j] = 0;
        __syncthreads();
        const unsigned mask_hi = (shift == 24) ? 0u : (0xFFFFFFFFu << (shift + 8));
        for (int i = tid; i < NP; i += 1024) {
            unsigned v = __float_as_uint(row[i]);
            if ((v & mask_hi) == (prefix & mask_hi))
                atomicAdd(&whist[wid][(v >> shift) & 0xFFu], 1u);
        }
        __syncthreads();
        if (tid < 256) {
            unsigned t = 0;
            for (int w = 0; w < 16; ++w) t += whist[w][tid];
            chist[tid] = t;
        }
        __syncthreads();
        if (tid < 64) {
            const unsigned cA = chist[4 * lane + 0];
            const unsigned cB = chist[4 * lane + 1];
            const unsigned cC = chist[4 * lane + 2];
            const unsigned cD = chist[4 * lane + 3];
            const unsigned g = cA + cB + cC + cD;
            unsigned T = g;
            for (int d = 1; d < 64; d <<= 1) {
                unsigned t = __shfl_down(T, d, 64);
                if (lane + d < 64) T += t;
            }
            const unsigned E = T - g;
            const bool hit = (E < (unsigned)k) && ((unsigned)k <= T);
            unsigned long long msk = __ballot(hit);
            int wl = __ffsll(msk) - 1;
            if (lane == wl) {
                unsigned cum = E;
                int bsel = 4 * lane;
                int kn = k;
                const unsigned cc[4] = {cD, cC, cB, cA};
                for (int j = 0; j < 4; ++j) {
                    if (cum + cc[j] >= (unsigned)k) {
                        bsel = 4 * lane + 3 - j;
                        kn = k - (int)cum;
                        break;
                    }
                    cum += cc[j];
                }
                sh_bucket = bsel;
                sh_knew = kn;
            }
        }
        __syncthreads();
        prefix |= ((unsigned)sh_bucket) << shift;
        k = sh_knew;
        __syncthreads();
    }
    const float T = __uint_as_float(prefix);

    float msum = 0.f;
    int mcnt = 0;
    for (int i = tid; i < NP; i += 1024) {
        float v = row[i];
        if (__float_as_uint(v) > prefix) { msum += v; mcnt++; }
    }
    for (int s = 32; s > 0; s >>= 1) {
        msum += __shfl_down(msum, s, 64);
        mcnt += __shfl_down(mcnt, s, 64);
    }
    if (lane == 0) { wsum[wid] = msum; wcnt[wid] = mcnt; }
    __syncthreads();
    if (tid == 0) {
        float tot = 0.f;
        int cnt = 0;
        for (int w = 0; w < 16; ++w) { tot += wsum[w]; cnt += wcnt[w]; }
        atomicAdd(&accB[b * 2 + 1], tot + (float)(K0 - cnt) * T);
    }
}

// ---------------------------------------------------------------- final
__global__ void k_final(const int* __restrict__ npos,
                        const float* __restrict__ accB,
                        float* __restrict__ out) {
    if (threadIdx.x == 0 && blockIdx.x == 0) {
        int n = 0;
        float a0 = 0.f, a1 = 0.f;
        for (int b = 0; b < NB; ++b) {
            n += npos[b];
            a0 += accB[b * 2 + 0];
            a1 += accB[b * 2 + 1];
        }
        const float N = (float)n;
        out[0] = a0 / N;
        out[1] = a1 / N;
    }
}

extern "C" void kernel_launch(void* const* d_in, const int* in_sizes, int n_in,
                              void* d_out, int out_size, void* d_ws, size_t ws_size,
                              hipStream_t stream) {
    const float* pred   = (const float*)d_in[0];
    const float* tboxes = (const float*)d_in[1];
    const int*   tlabels = (const int*)d_in[2];
    const float* priors = (const float*)d_in[3];
    float* out = (float*)d_out;

    char* w = (char*)d_ws;
    float2* bt2 = (float2*)w;                       // 8*BPCNT bytes
    float*  lrk = (float*)(w + 8ull * BPCNT);       // 4*BPCNT bytes
    u64*    mcand = (u64*)(w + 8ull * BPCNT);       // aliases lrk (safe: k_match
                                                    // writes, k_scatter reads,
                                                    // then k_main overwrites)
    int*    npos = (int*)(w + 12ull * BPCNT);       // NB i32
    float*  accB = (float*)(w + 12ull * BPCNT + 4ull * NB);  // NB*2 f32

    k_init<<<dim3(1), dim3(64), 0, stream>>>(npos, accB);
    k_match<<<dim3(MBLK, NB), dim3(256), 0, stream>>>(tboxes, priors, bt2, mcand);
    k_scatter<<<dim3(1), dim3(NB * NO), 0, stream>>>(mcand, bt2);
    k_main<<<dim3((NP + 63) / 64, NB), dim3(256), 0, stream>>>(
        pred, tboxes, tlabels, priors, bt2, lrk, npos, accB);
    k_select<<<dim3(NB), dim3(1024), 0, stream>>>(lrk, npos, accB);
    k_final<<<dim3(1), dim3(1), 0, stream>>>(npos, accB, out);
}

// Round 7
// 131.903 us; speedup vs baseline: 2.9879x; 2.9879x over previous
//
#include <hip/hip_runtime.h>
#include <math.h>

#define NB 32
#define NP 24656
#define NO 16
#define NC 81
#define ND 85   // 4 + NC
#define THRESH_F 0.5f
#define NEGPOS_I 3
#define VAR0_F 0.1f
#define VAR1_F 0.2f
#define NEG_HUGE -1e30f

#define BPCNT (NB * NP)
#define MBLK2 25         // k_match blocks per batch row = ceil(NP/1024)
#define CHB 386          // 64-row chunks per batch row = ceil(NP/64)
#define SPB 24           // k_main spans (blocks) per batch row
#define CBYTES 22528     // staged bytes per chunk = 22 x 1024

typedef unsigned long long u64;

// ---------------------------------------------------------------- init
__global__ void k_init(int* __restrict__ npos, float* __restrict__ accB) {
    int t = threadIdx.x;
    if (t < NB) npos[t] = 0;
    if (t < 2 * NB) accB[t] = 0.f;
}

// ---------------------------------------------------------------- match
// 4 priors per thread: 16x fewer cross-lane reduce ops per prior.
// per (b,p): best truth over O (strict >, first-max). per (b,o): block
// candidate key (iou_bits<<32 | ~p) -> mcand, reduced in k_scatter.
__global__ __launch_bounds__(256) void k_match(
    const float* __restrict__ tboxes, const float* __restrict__ priors,
    float2* __restrict__ bt2, u64* __restrict__ mcand) {
    const int b = blockIdx.y, bx = blockIdx.x, tid = threadIdx.x;
    const int lane = tid & 63, wv = tid >> 6;
    __shared__ float tb[NO * 4];
    __shared__ u64 wkey[4][NO];
    if (tid < NO * 4) tb[tid] = tboxes[b * NO * 4 + tid];
    __syncthreads();

    const int p0 = bx * 1024 + tid * 4;
    float pl[4], pt[4], prr[4], pbm[4], pa[4];
    bool pv[4];
#pragma unroll
    for (int j = 0; j < 4; ++j) {
        const int p = p0 + j;
        pv[j] = (p < NP);
        const float4 q = pv[j] ? ((const float4*)priors)[p]
                               : make_float4(0.f, 0.f, 1.f, 1.f);
        pl[j] = q.x - q.z * 0.5f; pt[j] = q.y - q.w * 0.5f;
        prr[j] = q.x + q.z * 0.5f; pbm[j] = q.y + q.w * 0.5f;
        pa[j] = (prr[j] - pl[j]) * (pbm[j] - pt[j]);
    }
    float bestv[4] = {-1.f, -1.f, -1.f, -1.f};
    int besti[4] = {0, 0, 0, 0};
    for (int o = 0; o < NO; ++o) {
        const float al = tb[o * 4], at = tb[o * 4 + 1];
        const float ar = tb[o * 4 + 2], ab = tb[o * 4 + 3];
        const float aarea = (ar - al) * (ab - at);
        u64 kmax = 0ull;
#pragma unroll
        for (int j = 0; j < 4; ++j) {
            float iw = fminf(ar, prr[j]) - fmaxf(al, pl[j]); iw = fmaxf(iw, 0.f);
            float ih = fminf(ab, pbm[j]) - fmaxf(at, pt[j]); ih = fmaxf(ih, 0.f);
            const float inter = iw * ih;
            const float iou = inter / (aarea + pa[j] - inter);
            if (pv[j]) {
                if (iou > bestv[j]) { bestv[j] = iou; besti[j] = o; }
                const u64 key = ((u64)__float_as_uint(iou) << 32) |
                                (u64)(0xFFFFFFFFu - (unsigned)(p0 + j));
                kmax = (key > kmax) ? key : kmax;
            }
        }
        for (int d = 1; d < 64; d <<= 1) {
            const u64 other = __shfl_xor(kmax, d, 64);
            kmax = (other > kmax) ? other : kmax;
        }
        if (lane == 0) wkey[wv][o] = kmax;
    }
#pragma unroll
    for (int j = 0; j < 4; ++j)
        if (pv[j])
            bt2[(size_t)b * NP + p0 + j] =
                make_float2(bestv[j], __int_as_float(besti[j]));
    __syncthreads();
    if (tid < NO) {
        u64 k0 = wkey[0][tid];
        k0 = (wkey[1][tid] > k0) ? wkey[1][tid] : k0;
        k0 = (wkey[2][tid] > k0) ? wkey[2][tid] : k0;
        k0 = (wkey[3][tid] > k0) ? wkey[3][tid] : k0;
        mcand[((size_t)(b * NO + tid)) * MBLK2 + bx] = k0;
    }
}

// ---------------------------------------------------------------- scatter
__global__ __launch_bounds__(512) void k_scatter(const u64* __restrict__ mcand,
                                                 float2* __restrict__ bt2) {
    __shared__ int pbest[NB * NO];
    const int t = threadIdx.x;
    const u64* c = mcand + (size_t)t * MBLK2;
    u64 best = 0ull;
    for (int i = 0; i < MBLK2; ++i) {
        const u64 v = c[i];
        best = (v > best) ? v : best;
    }
    pbest[t] = (int)(0xFFFFFFFFu - (unsigned)(best & 0xFFFFFFFFull));
    __syncthreads();
    if (t < NB) {
        for (int o = 0; o < NO; ++o) {
            const int p = pbest[t * NO + o];
            bt2[(size_t)t * NP + p] = make_float2(2.0f, __int_as_float(o));
        }
    }
}

// ---------------------------------------------------------------- stage
// 22 x 1KB contiguous global_load_lds (m13/m97-proven streaming shape).
// LDS dst = wave-uniform base (+ lane*16 by HW); global src per-lane.
__device__ __forceinline__ void stage_chunk(const char* __restrict__ gpred,
                                            int b, int r0, char* ldsbuf,
                                            int lane) {
    const size_t off = ((size_t)b * NP + r0) * (size_t)(ND * 4);
    const char* g = gpred + off;
    const bool unsafe = (b == NB - 1) && (r0 + 64 > NP);  // only b=31,r0=24640
    if (!unsafe) {
#pragma unroll
        for (int k = 0; k < 22; ++k)
            __builtin_amdgcn_global_load_lds(
                (const __attribute__((address_space(1))) void*)(g + k * 1024 +
                                                               lane * 16),
                (__attribute__((address_space(3))) void*)(ldsbuf + k * 1024),
                16, 0, 0);
    } else {
        const int nf4 = (NP - r0) * ND / 4;  // 16 rows -> 340 float4
        const float4* gs = (const float4*)g;
        float4* ld = (float4*)ldsbuf;
        for (int i = lane; i < nf4; i += 64) ld[i] = gs[i];
    }
}

// ---------------------------------------------------------------- main fused
// 1 wave per block, double-buffered 64-row chunks, wave-synchronous (no
// __syncthreads). Phase B: lane-per-row ds_read_b128 at aligned slots
// (A = 16*(21*l + l>>2), c0 = l&3; bank spread 21l mod 32 -> 2-way = free),
// R4-verified edge masking, 81-class softmax fully in registers.
__global__ __launch_bounds__(64) void k_main(
    const float* __restrict__ pred, const float* __restrict__ tboxes,
    const int* __restrict__ tlabels, const float* __restrict__ priors,
    const float2* __restrict__ bt2,
    float* __restrict__ lr, int* __restrict__ npos, float* __restrict__ accB) {
    __shared__ float4 smem[2][CBYTES / 16];

    const int b = blockIdx.y;
    const int span = blockIdx.x;
    const int lane = threadIdx.x;
    const size_t bbase = (size_t)b * NP;
    const char* gpred = (const char*)pred;

    char* cur = (char*)smem[0];
    char* nxt = (char*)smem[1];

    const int Ab = 16 * (21 * lane + (lane >> 2));
    const int c0 = lane & 3;

    float my_ll = 0.f, my_ce = 0.f;
    int my_np = 0;

    int chunk = span;
    if (chunk < CHB) stage_chunk(gpred, b, chunk * 64, cur, lane);
    int next_chunk = chunk + SPB;

    while (chunk < CHB) {
        if (next_chunk < CHB) {
            stage_chunk(gpred, b, next_chunk * 64, nxt, lane);
            asm volatile("s_waitcnt vmcnt(22)" ::: "memory");
        } else {
            asm volatile("s_waitcnt vmcnt(0)" ::: "memory");
        }

        const int r0 = chunk * 64;
        const int nrows = min(64, NP - r0);

        float4 v[22];
#pragma unroll
        for (int k = 0; k < 22; ++k)
            v[k] = *(const float4*)(cur + Ab + 16 * k);

        // background logit = window dword (c0+4) = v[1][c0]
        const float bg = (c0 == 0) ? v[1].x : (c0 == 1) ? v[1].y
                       : (c0 == 2) ? v[1].z : v[1].w;
        // masked head (slot 1): component t invalid iff t < c0
        float4 h = v[1];
        h.x = (c0 >= 1) ? NEG_HUGE : h.x;
        h.y = (c0 >= 2) ? NEG_HUGE : h.y;
        h.z = (c0 >= 3) ? NEG_HUGE : h.z;
        // masked tail (slot 21): component t invalid iff t > c0
        float4 t4 = v[21];
        t4.y = (c0 < 1) ? NEG_HUGE : t4.y;
        t4.z = (c0 < 2) ? NEG_HUGE : t4.z;
        t4.w = (c0 < 3) ? NEG_HUGE : t4.w;

        float4 MA = h, MB = t4;
#pragma unroll
        for (int k = 2; k < 21; k += 2) {
            MA.x = fmaxf(MA.x, v[k].x); MA.y = fmaxf(MA.y, v[k].y);
            MA.z = fmaxf(MA.z, v[k].z); MA.w = fmaxf(MA.w, v[k].w);
        }
#pragma unroll
        for (int k = 3; k < 21; k += 2) {
            MB.x = fmaxf(MB.x, v[k].x); MB.y = fmaxf(MB.y, v[k].y);
            MB.z = fmaxf(MB.z, v[k].z); MB.w = fmaxf(MB.w, v[k].w);
        }
        const float m = fmaxf(fmaxf(fmaxf(MA.x, MB.x), fmaxf(MA.y, MB.y)),
                              fmaxf(fmaxf(MA.z, MB.z), fmaxf(MA.w, MB.w)));

        float sA = __expf(h.x - m) + __expf(h.y - m) +
                   __expf(h.z - m) + __expf(h.w - m);
        float sB = __expf(t4.x - m) + __expf(t4.y - m) +
                   __expf(t4.z - m) + __expf(t4.w - m);
#pragma unroll
        for (int k = 2; k < 21; k += 2)
            sA += __expf(v[k].x - m) + __expf(v[k].y - m) +
                  __expf(v[k].z - m) + __expf(v[k].w - m);
#pragma unroll
        for (int k = 3; k < 21; k += 2)
            sB += __expf(v[k].x - m) + __expf(v[k].y - m) +
                  __expf(v[k].z - m) + __expf(v[k].w - m);
        const float lse = m + __logf(sA + sB);

        if (lane < nrows) {
            const int p = r0 + lane;
            const float2 bt = bt2[bbase + p];
            const bool pos = (bt.x >= THRESH_F);
            const int o = __float_as_int(bt.y);
            lr[bbase + p] = pos ? 0.f : (lse - bg);
            if (pos) {
                my_np += 1;
                const int lbl = tlabels[b * NO + o] + 1;
                const float val = *(const float*)(cur + 340 * lane + (4 + lbl) * 4);
                my_ce += lse - val;
                const float4 pq = *((const float4*)priors + p);
                const float tx0 = tboxes[(b * NO + o) * 4 + 0];
                const float ty0 = tboxes[(b * NO + o) * 4 + 1];
                const float tx1 = tboxes[(b * NO + o) * 4 + 2];
                const float ty1 = tboxes[(b * NO + o) * 4 + 3];
                // loc = window dwords c0..c0+3 from v[0]/v[1]
                const float l0 = (c0 == 0) ? v[0].x : (c0 == 1) ? v[0].y
                               : (c0 == 2) ? v[0].z : v[0].w;
                const float l1 = (c0 == 0) ? v[0].y : (c0 == 1) ? v[0].z
                               : (c0 == 2) ? v[0].w : v[1].x;
                const float l2 = (c0 == 0) ? v[0].z : (c0 == 1) ? v[0].w
                               : (c0 == 2) ? v[1].x : v[1].y;
                const float l3 = (c0 == 0) ? v[0].w : (c0 == 1) ? v[1].x
                               : (c0 == 2) ? v[1].y : v[1].z;
                const float g0 = ((tx0 + tx1) * 0.5f - pq.x) / (VAR0_F * pq.z);
                const float g1 = ((ty0 + ty1) * 0.5f - pq.y) / (VAR0_F * pq.w);
                const float g2 = __logf((tx1 - tx0) / pq.z) / VAR1_F;
                const float g3 = __logf((ty1 - ty0) / pq.w) / VAR1_F;
                float dd, ad;
                dd = l0 - g0; ad = fabsf(dd); my_ll += (ad < 1.f) ? 0.5f * dd * dd : (ad - 0.5f);
                dd = l1 - g1; ad = fabsf(dd); my_ll += (ad < 1.f) ? 0.5f * dd * dd : (ad - 0.5f);
                dd = l2 - g2; ad = fabsf(dd); my_ll += (ad < 1.f) ? 0.5f * dd * dd : (ad - 0.5f);
                dd = l3 - g3; ad = fabsf(dd); my_ll += (ad < 1.f) ? 0.5f * dd * dd : (ad - 0.5f);
            }
        }
        chunk = next_chunk;
        next_chunk += SPB;
        char* tmp = cur; cur = nxt; nxt = tmp;
    }

    for (int d2 = 1; d2 < 64; d2 <<= 1) {
        my_ll += __shfl_xor(my_ll, d2, 64);
        my_ce += __shfl_xor(my_ce, d2, 64);
        my_np += __shfl_xor(my_np, d2, 64);
    }
    if (lane == 0) {
        if (my_ll != 0.f) atomicAdd(&accB[b * 2 + 0], my_ll);
        if (my_ce != 0.f) atomicAdd(&accB[b * 2 + 1], my_ce);
        if (my_np) atomicAdd(&npos[b], my_np);
    }
}

// ---------------------------------------------------------------- select
__global__ __launch_bounds__(1024) void k_select(
    const float* __restrict__ lrk, const int* __restrict__ npos,
    float* __restrict__ accB) {
    const int b = blockIdx.x;
    const float* row = lrk + (size_t)b * NP;
    const int tid = threadIdx.x;
    const int lane = tid & 63;
    const int wid = tid >> 6;

    __shared__ unsigned whist[16][256];
    __shared__ unsigned chist[256];
    __shared__ int sh_bucket, sh_knew;
    __shared__ float wsum[16];
    __shared__ int wcnt[16];

    const int K0 = min(npos[b] * NEGPOS_I, NP);
    int k = K0;
    unsigned prefix = 0;

    for (int shift = 24; shift >= 0; shift -= 8) {
        for (int j = lane; j < 256; j += 64) whist[wid][j] = 0;
        __syncthreads();
        const unsigned mask_hi = (shift == 24) ? 0u : (0xFFFFFFFFu << (shift + 8));
        for (int i = tid; i < NP; i += 1024) {
            unsigned v = __float_as_uint(row[i]);
            if ((v & mask_hi) == (prefix & mask_hi))
                atomicAdd(&whist[wid][(v >> shift) & 0xFFu], 1u);
        }
        __syncthreads();
        if (tid < 256) {
            unsigned t = 0;
            for (int w = 0; w < 16; ++w) t += whist[w][tid];
            chist[tid] = t;
        }
        __syncthreads();
        if (tid < 64) {
            const unsigned cA = chist[4 * lane + 0];
            const unsigned cB = chist[4 * lane + 1];
            const unsigned cC = chist[4 * lane + 2];
            const unsigned cD = chist[4 * lane + 3];
            const unsigned g = cA + cB + cC + cD;
            unsigned T = g;
            for (int d = 1; d < 64; d <<= 1) {
                unsigned t = __shfl_down(T, d, 64);
                if (lane + d < 64) T += t;
            }
            const unsigned E = T - g;
            const bool hit = (E < (unsigned)k) && ((unsigned)k <= T);
            unsigned long long msk = __ballot(hit);
            int wl = __ffsll(msk) - 1;
            if (lane == wl) {
                unsigned cum = E;
                int bsel = 4 * lane;
                int kn = k;
                const unsigned cc[4] = {cD, cC, cB, cA};
                for (int j = 0; j < 4; ++j) {
                    if (cum + cc[j] >= (unsigned)k) {
                        bsel = 4 * lane + 3 - j;
                        kn = k - (int)cum;
                        break;
                    }
                    cum += cc[j];
                }
                sh_bucket = bsel;
                sh_knew = kn;
            }
        }
        __syncthreads();
        prefix |= ((unsigned)sh_bucket) << shift;
        k = sh_knew;
        __syncthreads();
    }
    const float T = __uint_as_float(prefix);

    float msum = 0.f;
    int mcnt = 0;
    for (int i = tid; i < NP; i += 1024) {
        float v = row[i];
        if (__float_as_uint(v) > prefix) { msum += v; mcnt++; }
    }
    for (int s = 32; s > 0; s >>= 1) {
        msum += __shfl_down(msum, s, 64);
        mcnt += __shfl_down(mcnt, s, 64);
    }
    if (lane == 0) { wsum[wid] = msum; wcnt[wid] = mcnt; }
    __syncthreads();
    if (tid == 0) {
        float tot = 0.f;
        int cnt = 0;
        for (int w = 0; w < 16; ++w) { tot += wsum[w]; cnt += wcnt[w]; }
        atomicAdd(&accB[b * 2 + 1], tot + (float)(K0 - cnt) * T);
    }
}

// ---------------------------------------------------------------- final
__global__ void k_final(const int* __restrict__ npos,
                        const float* __restrict__ accB,
                        float* __restrict__ out) {
    if (threadIdx.x == 0 && blockIdx.x == 0) {
        int n = 0;
        float a0 = 0.f, a1 = 0.f;
        for (int b = 0; b < NB; ++b) {
            n += npos[b];
            a0 += accB[b * 2 + 0];
            a1 += accB[b * 2 + 1];
        }
        const float N = (float)n;
        out[0] = a0 / N;
        out[1] = a1 / N;
    }
}

extern "C" void kernel_launch(void* const* d_in, const int* in_sizes, int n_in,
                              void* d_out, int out_size, void* d_ws, size_t ws_size,
                              hipStream_t stream) {
    const float* pred   = (const float*)d_in[0];
    const float* tboxes = (const float*)d_in[1];
    const int*   tlabels = (const int*)d_in[2];
    const float* priors = (const float*)d_in[3];
    float* out = (float*)d_out;

    char* w = (char*)d_ws;
    float2* bt2 = (float2*)w;                       // 8*BPCNT bytes
    float*  lrk = (float*)(w + 8ull * BPCNT);       // 4*BPCNT bytes
    u64*    mcand = (u64*)(w + 8ull * BPCNT);       // aliases lrk (k_match
                                                    // writes, k_scatter reads,
                                                    // then k_main overwrites)
    int*    npos = (int*)(w + 12ull * BPCNT);       // NB i32
    float*  accB = (float*)(w + 12ull * BPCNT + 4ull * NB);  // NB*2 f32

    k_init<<<dim3(1), dim3(64), 0, stream>>>(npos, accB);
    k_match<<<dim3(MBLK2, NB), dim3(256), 0, stream>>>(tboxes, priors, bt2, mcand);
    k_scatter<<<dim3(1), dim3(NB * NO), 0, stream>>>(mcand, bt2);
    k_main<<<dim3(SPB, NB), dim3(64), 0, stream>>>(
        pred, tboxes, tlabels, priors, bt2, lrk, npos, accB);
    k_select<<<dim3(NB), dim3(1024), 0, stream>>>(lrk, npos, accB);
    k_final<<<dim3(1), dim3(1), 0, stream>>>(npos, accB, out);
}

// Round 9
// 124.017 us; speedup vs baseline: 3.1779x; 1.0636x over previous
//
#include <hip/hip_runtime.h>
#include <math.h>

#define NB 32
#define NP 24656
#define NO 16
#define NC 81
#define ND 85   // 4 + NC
#define THRESH_F 0.5f
#define NEGPOS_I 3
#define VAR0_F 0.1f
#define VAR1_F 0.2f
#define NEG_HUGE -1e30f

#define BPCNT (NB * NP)
#define MBLK2 25         // k_match blocks per batch row = ceil(NP/1024)
#define CHB 386          // 64-row chunks per batch row = ceil(NP/64)
#define SPB 24           // k_main spans (blocks) per batch row
#define CBYTES 22528     // staged bytes per chunk = 22 x 1024

typedef unsigned long long u64;

// ---------------------------------------------------------------- match
// 4 priors/thread. per (b,p): best truth over O (strict >, first-max) -> bt2.
// per (b,o): block candidate key (iou_bits<<32 | ~p) -> mcand (reduced in
// k_main's prologue). Block (0,0) also zeroes npos/accB/done (init merged).
__global__ __launch_bounds__(256) void k_match(
    const float* __restrict__ tboxes, const float* __restrict__ priors,
    float2* __restrict__ bt2, u64* __restrict__ mcand,
    int* __restrict__ npos, float* __restrict__ accB, int* __restrict__ done) {
    const int b = blockIdx.y, bx = blockIdx.x, tid = threadIdx.x;
    const int lane = tid & 63, wv = tid >> 6;
    __shared__ float tb[NO * 4];
    __shared__ u64 wkey[4][NO];
    if (bx == 0 && b == 0) {  // merged k_init (consumed only by later kernels)
        if (tid < NB) npos[tid] = 0;
        if (tid < 2 * NB) accB[tid] = 0.f;
        if (tid == 0) *done = 0;
    }
    if (tid < NO * 4) tb[tid] = tboxes[b * NO * 4 + tid];
    __syncthreads();

    const int p0 = bx * 1024 + tid * 4;
    float pl[4], pt[4], prr[4], pbm[4], pa[4];
    bool pv[4];
#pragma unroll
    for (int j = 0; j < 4; ++j) {
        const int p = p0 + j;
        pv[j] = (p < NP);
        const float4 q = pv[j] ? ((const float4*)priors)[p]
                               : make_float4(0.f, 0.f, 1.f, 1.f);
        pl[j] = q.x - q.z * 0.5f; pt[j] = q.y - q.w * 0.5f;
        prr[j] = q.x + q.z * 0.5f; pbm[j] = q.y + q.w * 0.5f;
        pa[j] = (prr[j] - pl[j]) * (pbm[j] - pt[j]);
    }
    float bestv[4] = {-1.f, -1.f, -1.f, -1.f};
    int besti[4] = {0, 0, 0, 0};
    for (int o = 0; o < NO; ++o) {
        const float al = tb[o * 4], at = tb[o * 4 + 1];
        const float ar = tb[o * 4 + 2], ab = tb[o * 4 + 3];
        const float aarea = (ar - al) * (ab - at);
        u64 kmax = 0ull;
#pragma unroll
        for (int j = 0; j < 4; ++j) {
            float iw = fminf(ar, prr[j]) - fmaxf(al, pl[j]); iw = fmaxf(iw, 0.f);
            float ih = fminf(ab, pbm[j]) - fmaxf(at, pt[j]); ih = fmaxf(ih, 0.f);
            const float inter = iw * ih;
            const float iou = inter / (aarea + pa[j] - inter);
            if (pv[j]) {
                if (iou > bestv[j]) { bestv[j] = iou; besti[j] = o; }
                const u64 key = ((u64)__float_as_uint(iou) << 32) |
                                (u64)(0xFFFFFFFFu - (unsigned)(p0 + j));
                kmax = (key > kmax) ? key : kmax;
            }
        }
        for (int d = 1; d < 64; d <<= 1) {
            const u64 other = __shfl_xor(kmax, d, 64);
            kmax = (other > kmax) ? other : kmax;
        }
        if (lane == 0) wkey[wv][o] = kmax;
    }
#pragma unroll
    for (int j = 0; j < 4; ++j)
        if (pv[j])
            bt2[(size_t)b * NP + p0 + j] =
                make_float2(bestv[j], __int_as_float(besti[j]));
    __syncthreads();
    if (tid < NO) {
        u64 k0 = wkey[0][tid];
        k0 = (wkey[1][tid] > k0) ? wkey[1][tid] : k0;
        k0 = (wkey[2][tid] > k0) ? wkey[2][tid] : k0;
        k0 = (wkey[3][tid] > k0) ? wkey[3][tid] : k0;
        mcand[((size_t)(b * NO + tid)) * MBLK2 + bx] = k0;
    }
}

// ---------------------------------------------------------------- stage
// 22 x 1KB contiguous global_load_lds (m13/m97-proven streaming shape).
__device__ __forceinline__ void stage_chunk(const char* __restrict__ gpred,
                                            int b, int r0, char* ldsbuf,
                                            int lane) {
    const size_t off = ((size_t)b * NP + r0) * (size_t)(ND * 4);
    const char* g = gpred + off;
    const bool unsafe = (b == NB - 1) && (r0 + 64 > NP);  // only b=31,r0=24640
    if (!unsafe) {
#pragma unroll
        for (int k = 0; k < 22; ++k)
            __builtin_amdgcn_global_load_lds(
                (const __attribute__((address_space(1))) void*)(g + k * 1024 +
                                                               lane * 16),
                (__attribute__((address_space(3))) void*)(ldsbuf + k * 1024),
                16, 0, 0);
    } else {
        const int nf4 = (NP - r0) * ND / 4;  // 16 rows -> 340 float4
        const float4* gs = (const float4*)g;
        float4* ld = (float4*)ldsbuf;
        for (int i = lane; i < nf4; i += 64) ld[i] = gs[i];
    }
}

// ---------------------------------------------------------------- main fused
// 1 wave/block, double-buffered 64-row chunks, wave-synchronous. Prologue
// re-reduces mcand (scatter kernel eliminated): forced-positive override
// via 16 register compares per row (ascending-j overwrite = last-o-wins).
__global__ __launch_bounds__(64) void k_main(
    const float* __restrict__ pred, const float* __restrict__ tboxes,
    const int* __restrict__ tlabels, const float* __restrict__ priors,
    const float2* __restrict__ bt2, const u64* __restrict__ mcand,
    float* __restrict__ lr, int* __restrict__ npos, float* __restrict__ accB) {
    __shared__ float4 smem[2][CBYTES / 16];

    const int b = blockIdx.y;
    const int span = blockIdx.x;
    const int lane = threadIdx.x;
    const size_t bbase = (size_t)b * NP;
    const char* gpred = (const char*)pred;

    char* cur = (char*)smem[0];
    char* nxt = (char*)smem[1];

    const int Ab = 16 * (21 * lane + (lane >> 2));
    const int c0 = lane & 3;

    // prologue: per-o best prior for this b (lanes 0..15), broadcast to all
    u64 pbk = 0ull;
    if (lane < NO) {
        const u64* c = mcand + (size_t)(b * NO + lane) * MBLK2;
        for (int i = 0; i < MBLK2; ++i) {
            const u64 v = c[i];
            pbk = (v > pbk) ? v : pbk;
        }
    }
    int p16[NO];
#pragma unroll
    for (int j = 0; j < NO; ++j) {
        const u64 kj = __shfl(pbk, j, 64);
        p16[j] = (int)(0xFFFFFFFFu - (unsigned)(kj & 0xFFFFFFFFull));
    }

    float my_ll = 0.f, my_ce = 0.f;
    int my_np = 0;

    int chunk = span;
    if (chunk < CHB) stage_chunk(gpred, b, chunk * 64, cur, lane);
    int next_chunk = chunk + SPB;

    while (chunk < CHB) {
        if (next_chunk < CHB) {
            stage_chunk(gpred, b, next_chunk * 64, nxt, lane);
            asm volatile("s_waitcnt vmcnt(22)" ::: "memory");
        } else {
            asm volatile("s_waitcnt vmcnt(0)" ::: "memory");
        }

        const int r0 = chunk * 64;
        const int nrows = min(64, NP - r0);

        float4 v[22];
#pragma unroll
        for (int k = 0; k < 22; ++k)
            v[k] = *(const float4*)(cur + Ab + 16 * k);

        const float bg = (c0 == 0) ? v[1].x : (c0 == 1) ? v[1].y
                       : (c0 == 2) ? v[1].z : v[1].w;
        float4 h = v[1];
        h.x = (c0 >= 1) ? NEG_HUGE : h.x;
        h.y = (c0 >= 2) ? NEG_HUGE : h.y;
        h.z = (c0 >= 3) ? NEG_HUGE : h.z;
        float4 t4 = v[21];
        t4.y = (c0 < 1) ? NEG_HUGE : t4.y;
        t4.z = (c0 < 2) ? NEG_HUGE : t4.z;
        t4.w = (c0 < 3) ? NEG_HUGE : t4.w;

        float4 MA = h, MB = t4;
#pragma unroll
        for (int k = 2; k < 21; k += 2) {
            MA.x = fmaxf(MA.x, v[k].x); MA.y = fmaxf(MA.y, v[k].y);
            MA.z = fmaxf(MA.z, v[k].z); MA.w = fmaxf(MA.w, v[k].w);
        }
#pragma unroll
        for (int k = 3; k < 21; k += 2) {
            MB.x = fmaxf(MB.x, v[k].x); MB.y = fmaxf(MB.y, v[k].y);
            MB.z = fmaxf(MB.z, v[k].z); MB.w = fmaxf(MB.w, v[k].w);
        }
        const float m = fmaxf(fmaxf(fmaxf(MA.x, MB.x), fmaxf(MA.y, MB.y)),
                              fmaxf(fmaxf(MA.z, MB.z), fmaxf(MA.w, MB.w)));

        float sA = __expf(h.x - m) + __expf(h.y - m) +
                   __expf(h.z - m) + __expf(h.w - m);
        float sB = __expf(t4.x - m) + __expf(t4.y - m) +
                   __expf(t4.z - m) + __expf(t4.w - m);
#pragma unroll
        for (int k = 2; k < 21; k += 2)
            sA += __expf(v[k].x - m) + __expf(v[k].y - m) +
                  __expf(v[k].z - m) + __expf(v[k].w - m);
#pragma unroll
        for (int k = 3; k < 21; k += 2)
            sB += __expf(v[k].x - m) + __expf(v[k].y - m) +
                  __expf(v[k].z - m) + __expf(v[k].w - m);
        const float lse = m + __logf(sA + sB);

        if (lane < nrows) {
            const int p = r0 + lane;
            const float2 bt = bt2[bbase + p];
            int o_f = -1;
#pragma unroll
            for (int j = 0; j < NO; ++j)
                if (p == p16[j]) o_f = j;   // ascending j = last-o-wins
            const bool forced = (o_f >= 0);
            const bool pos = forced || (bt.x >= THRESH_F);
            const int o = forced ? o_f : __float_as_int(bt.y);
            lr[bbase + p] = pos ? 0.f : (lse - bg);
            if (pos) {
                my_np += 1;
                const int lbl = tlabels[b * NO + o] + 1;
                const float val = *(const float*)(cur + 340 * lane + (4 + lbl) * 4);
                my_ce += lse - val;
                const float4 pq = *((const float4*)priors + p);
                const float tx0 = tboxes[(b * NO + o) * 4 + 0];
                const float ty0 = tboxes[(b * NO + o) * 4 + 1];
                const float tx1 = tboxes[(b * NO + o) * 4 + 2];
                const float ty1 = tboxes[(b * NO + o) * 4 + 3];
                const float l0 = (c0 == 0) ? v[0].x : (c0 == 1) ? v[0].y
                               : (c0 == 2) ? v[0].z : v[0].w;
                const float l1 = (c0 == 0) ? v[0].y : (c0 == 1) ? v[0].z
                               : (c0 == 2) ? v[0].w : v[1].x;
                const float l2 = (c0 == 0) ? v[0].z : (c0 == 1) ? v[0].w
                               : (c0 == 2) ? v[1].x : v[1].y;
                const float l3 = (c0 == 0) ? v[0].w : (c0 == 1) ? v[1].x
                               : (c0 == 2) ? v[1].y : v[1].z;
                const float g0 = ((tx0 + tx1) * 0.5f - pq.x) / (VAR0_F * pq.z);
                const float g1 = ((ty0 + ty1) * 0.5f - pq.y) / (VAR0_F * pq.w);
                const float g2 = __logf((tx1 - tx0) / pq.z) / VAR1_F;
                const float g3 = __logf((ty1 - ty0) / pq.w) / VAR1_F;
                float dd, ad;
                dd = l0 - g0; ad = fabsf(dd); my_ll += (ad < 1.f) ? 0.5f * dd * dd : (ad - 0.5f);
                dd = l1 - g1; ad = fabsf(dd); my_ll += (ad < 1.f) ? 0.5f * dd * dd : (ad - 0.5f);
                dd = l2 - g2; ad = fabsf(dd); my_ll += (ad < 1.f) ? 0.5f * dd * dd : (ad - 0.5f);
                dd = l3 - g3; ad = fabsf(dd); my_ll += (ad < 1.f) ? 0.5f * dd * dd : (ad - 0.5f);
            }
        }
        chunk = next_chunk;
        next_chunk += SPB;
        char* tmp = cur; cur = nxt; nxt = tmp;
    }

    for (int d2 = 1; d2 < 64; d2 <<= 1) {
        my_ll += __shfl_xor(my_ll, d2, 64);
        my_ce += __shfl_xor(my_ce, d2, 64);
        my_np += __shfl_xor(my_np, d2, 64);
    }
    if (lane == 0) {
        if (my_ll != 0.f) atomicAdd(&accB[b * 2 + 0], my_ll);
        if (my_ce != 0.f) atomicAdd(&accB[b * 2 + 1], my_ce);
        if (my_np) atomicAdd(&npos[b], my_np);
    }
}

// ---------------------------------------------------------------- select
// per b: 3-pass radix (11/11/10 bits, 2048-bin shared hist) for K-th largest
// T, then sum pass: negsum = sum(v>T) + (K - cnt)*T. Last-finishing block
// computes the final outputs (k_final merged).
__global__ __launch_bounds__(1024) void k_select(
    const float* __restrict__ lrk, const int* __restrict__ npos,
    float* __restrict__ accB, int* __restrict__ done, float* __restrict__ out) {
    const int b = blockIdx.x;
    const float* row = lrk + (size_t)b * NP;
    const int tid = threadIdx.x;
    const int lane = tid & 63;
    const int wid = tid >> 6;

    __shared__ unsigned hist[2048];
    __shared__ int sh_bucket, sh_knew;
    __shared__ float wsum[16];
    __shared__ int wcnt[16];

    const int K0 = min(npos[b] * NEGPOS_I, NP);
    int k = K0;
    unsigned prefix = 0;

    const int shifts[3] = {21, 10, 0};
    const unsigned masks[3] = {0u, 0xFFE00000u, 0xFFFFFC00u};

    for (int pass = 0; pass < 3; ++pass) {
        const int shift = shifts[pass];
        const unsigned mask_hi = masks[pass];
        hist[tid] = 0;
        hist[tid + 1024] = 0;
        __syncthreads();
        for (int i = tid; i < NP; i += 1024) {
            const unsigned v = __float_as_uint(row[i]);
            if ((v & mask_hi) == (prefix & mask_hi))
                atomicAdd(&hist[(v >> shift) & 2047u], 1u);
        }
        __syncthreads();
        if (tid < 64) {
            unsigned g = 0;
            for (int j = 0; j < 32; ++j) g += hist[lane * 32 + j];
            unsigned T = g;
            for (int d = 1; d < 64; d <<= 1) {
                const unsigned t = __shfl_down(T, d, 64);
                if (lane + d < 64) T += t;
            }
            const unsigned E = T - g;
            const bool hit = (E < (unsigned)k) && ((unsigned)k <= T);
            const unsigned long long msk = __ballot(hit);
            const int wl = __ffsll(msk) - 1;
            if (lane == wl) {
                unsigned cum = E;
                int bsel = lane * 32, kn = k;
                for (int j = 31; j >= 0; --j) {
                    const unsigned c = hist[lane * 32 + j];
                    if (cum + c >= (unsigned)k) {
                        bsel = lane * 32 + j;
                        kn = k - (int)cum;
                        break;
                    }
                    cum += c;
                }
                sh_bucket = bsel;
                sh_knew = kn;
            }
        }
        __syncthreads();
        prefix |= ((unsigned)sh_bucket) << shift;
        k = sh_knew;
        __syncthreads();
    }
    const float T = __uint_as_float(prefix);

    float msum = 0.f;
    int mcnt = 0;
    for (int i = tid; i < NP; i += 1024) {
        const float v = row[i];
        if (__float_as_uint(v) > prefix) { msum += v; mcnt++; }
    }
    for (int s = 32; s > 0; s >>= 1) {
        msum += __shfl_down(msum, s, 64);
        mcnt += __shfl_down(mcnt, s, 64);
    }
    if (lane == 0) { wsum[wid] = msum; wcnt[wid] = mcnt; }
    __syncthreads();
    if (tid == 0) {
        float tot = 0.f;
        int cnt = 0;
        for (int w = 0; w < 16; ++w) { tot += wsum[w]; cnt += wcnt[w]; }
        atomicAdd(&accB[b * 2 + 1], tot + (float)(K0 - cnt) * T);
        __threadfence();
        if (atomicAdd(done, 1) == NB - 1) {   // merged k_final
            volatile const float* va = accB;
            volatile const int* vn = npos;
            int n = 0;
            float a0 = 0.f, a1 = 0.f;
            for (int bb = 0; bb < NB; ++bb) {
                n += vn[bb];
                a0 += va[bb * 2 + 0];
                a1 += va[bb * 2 + 1];
            }
            const float N = (float)n;
            out[0] = a0 / N;
            out[1] = a1 / N;
        }
    }
}

extern "C" void kernel_launch(void* const* d_in, const int* in_sizes, int n_in,
                              void* d_out, int out_size, void* d_ws, size_t ws_size,
                              hipStream_t stream) {
    const float* pred   = (const float*)d_in[0];
    const float* tboxes = (const float*)d_in[1];
    const int*   tlabels = (const int*)d_in[2];
    const float* priors = (const float*)d_in[3];
    float* out = (float*)d_out;

    char* w = (char*)d_ws;
    float2* bt2 = (float2*)w;                         // 8*BPCNT bytes
    float*  lrk = (float*)(w + 8ull * BPCNT);         // 4*BPCNT bytes
    u64*    mcand = (u64*)(w + 12ull * BPCNT);        // NB*NO*MBLK2 u64 (100 KB)
    char*   w2 = w + 12ull * BPCNT + 8ull * NB * NO * MBLK2;
    int*    npos = (int*)w2;                          // NB i32
    float*  accB = (float*)(w2 + 4ull * NB);          // NB*2 f32
    int*    done = (int*)(w2 + 4ull * NB + 8ull * NB); // 1 i32

    k_match<<<dim3(MBLK2, NB), dim3(256), 0, stream>>>(
        tboxes, priors, bt2, mcand, npos, accB, done);
    k_main<<<dim3(SPB, NB), dim3(64), 0, stream>>>(
        pred, tboxes, tlabels, priors, bt2, mcand, lrk, npos, accB);
    k_select<<<dim3(NB), dim3(1024), 0, stream>>>(lrk, npos, accB, done, out);
}